// Round 4
// baseline (344.326 us; speedup 1.0000x reference)
//
#include <hip/hip_runtime.h>
#include <cstdint>
#include <cstddef>

typedef unsigned short u16;
typedef unsigned int   u32;

#define LW     15
#define BNS    0.9999950000374997f   /* 1/sqrt(1+1e-5) */
#define SCALE  0.17677669529663687f  /* 1/sqrt(32) */

typedef __bf16 bf16x8 __attribute__((ext_vector_type(8)));
typedef float  f32x4  __attribute__((ext_vector_type(4)));
typedef u16    u16x8  __attribute__((ext_vector_type(8)));

__device__ __forceinline__ u16 f2bf(float f){
  union { float f; u32 i; } v; v.f = f;
  u32 r = v.i + 0x7FFFu + ((v.i >> 16) & 1u);
  return (u16)(r >> 16);
}
__device__ __forceinline__ float bf2f(u16 u){
  union { u32 i; float f; } v; v.i = ((u32)u) << 16; return v.f;
}

// ---------------------------------------------------------------------------
// Kernel 0: convert qkv_w (196608) and proj_w (65536) fp32 -> bf16 in ws
// ---------------------------------------------------------------------------
__global__ void k_cvt_w(const float* __restrict__ qw, const float* __restrict__ pw,
                        u16* __restrict__ qwb, u16* __restrict__ pwb){
  const int i = blockIdx.x*256 + threadIdx.x;
  if (i < 196608) qwb[i] = f2bf(qw[i]);
  else            pwb[i - 196608] = f2bf(pw[i - 196608]);
}

// ---------------------------------------------------------------------------
// Kernel 1: CPB MLP -> tab[225][8] fp32
// ---------------------------------------------------------------------------
__global__ void k_cpb_mlp(const float* __restrict__ w1, const float* __restrict__ b1,
                          const float* __restrict__ w2, float* __restrict__ tab){
  const int e = blockIdx.x;        // 0..224
  const int c = threadIdx.x;       // 0..255
  const float a0 = (float)(e / LW - 7);
  const float a1 = (float)(e % LW - 7);
  const float cx = copysignf(log2f(fabsf(a0)*(8.f/7.f) + 1.f) * (1.f/3.f), a0);
  const float cy = copysignf(log2f(fabsf(a1)*(8.f/7.f) + 1.f) * (1.f/3.f), a1);
  float pre = (cx*w1[2*c] + cy*w1[2*c+1] + b1[c]) * BNS;
  float hid = pre / (1.f + __expf(-pre));   // silu
  __shared__ float hl[256];
  hl[c] = hid;
  __syncthreads();
  if (c < 8){
    float s = 0.f;
    for (int i = 0; i < 256; ++i) s += hl[i] * w2[c*256 + i];
    tab[e*8 + c] = s * BNS;
  }
}

// ---------------------------------------------------------------------------
// Kernel 2: biasQ[h][query q][key] = 16*sigmoid(tab[rpi(q,key)][h])
// ---------------------------------------------------------------------------
__global__ void k_bias_expand(const float* __restrict__ tab, float* __restrict__ biasQ){
  const int id = blockIdx.x*256 + threadIdx.x;   // h*4096 + q*64 + key
  const int key = id & 63;
  const int q   = (id >> 6) & 63;
  const int h   = id >> 12;
  const int dy = (q >> 3) - (key >> 3) + 7;
  const int dx = (q & 7)  - (key & 7)  + 7;
  const float v = tab[(dy*LW + dx)*8 + h];
  biasQ[id] = 16.f / (1.f + __expf(-v));
}

// ---------------------------------------------------------------------------
// Kernel 3: fused qkv GEMM + attention, WAVE-PER-HEAD, ONE barrier.
// Same structure as round 3, but per-wave bounce shrunk 4608 -> 2304 B:
//   q/k: quarter-tile bounce [16 tok][40 d] (1280 B), 4 sequential quarters
//   P:   [16 q][72 key] (2304 B)
//   v:   two 16-d halves [16 d][72 tok] (2304 B) + split V-store per half
// LDS: xs 33792 + 8*2304 = 52224 -> up to 3 blocks/CU if regs allow.
// ---------------------------------------------------------------------------
__global__ __launch_bounds__(512, 4) void k_qkv_attn(
    const float* __restrict__ x, const u16* __restrict__ qwb,
    const float* __restrict__ qb, const float* __restrict__ biasQ,
    float* __restrict__ xout, u16* __restrict__ vout){
  const int win = blockIdx.x;
  const int b = win >> 6, wy = (win >> 3) & 7, wx = win & 7;
  __shared__ __align__(16) char smem[52224];
  u16* xs = (u16*)smem;                              // [64 tok][264 c]
  const int tid  = threadIdx.x;
  const int wave = tid >> 6, lane = tid & 63;
  const int quad = lane >> 4, l16 = lane & 15;
  u16* vbw = (u16*)(smem + 33792 + wave*2304);       // per-wave bounce

  // ---- stage x -> xs bf16 [tok][c] ----
  const float* xbase = x + (size_t)b*256*4096 + (size_t)(wy*8)*64 + wx*8;
  for (int i = tid; i < 4096; i += 512){
    const int c  = i >> 4;
    const int g  = i & 15;
    const int py = g >> 1, xh = (g & 1) * 4;
    float4 v4 = *(const float4*)&xbase[(size_t)c*4096 + py*64 + xh];
    const int n0 = py*8 + xh;
    xs[(n0+0)*264 + c] = f2bf(v4.x);
    xs[(n0+1)*264 + c] = f2bf(v4.y);
    xs[(n0+2)*264 + c] = f2bf(v4.z);
    xs[(n0+3)*264 + c] = f2bf(v4.w);
  }
  __syncthreads();   // the ONLY barrier

  const int h = wave;
  const f32x4 zero4 = {0.f, 0.f, 0.f, 0.f};

  // GEMM for one section (0=q,1=k,2=v): 2 row-tiles x 4 token-tiles, K=256.
  auto run_gemm = [&](int sec, u32 (&w)[2][4][2]){
    f32x4 acc[2][4];
    #pragma unroll
    for (int rt = 0; rt < 2; ++rt)
      #pragma unroll
      for (int tt = 0; tt < 4; ++tt) acc[rt][tt] = zero4;
    #pragma unroll
    for (int kh2 = 0; kh2 < 2; ++kh2){
      bf16x8 af[2][4];
      #pragma unroll
      for (int rt = 0; rt < 2; ++rt){
        const int wr = sec*256 + h*32 + rt*16 + l16;
        #pragma unroll
        for (int kc = 0; kc < 4; ++kc)
          af[rt][kc] = *(const bf16x8*)(qwb + (size_t)wr*256 + (kh2*4 + kc)*32 + quad*8);
      }
      #pragma unroll
      for (int kc = 0; kc < 4; ++kc){
        #pragma unroll
        for (int tt = 0; tt < 4; ++tt){
          bf16x8 bf = *(const bf16x8*)&xs[(tt*16 + l16)*264 + (kh2*4 + kc)*32 + quad*8];
          acc[0][tt] = __builtin_amdgcn_mfma_f32_16x16x32_bf16(af[0][kc], bf, acc[0][tt], 0, 0, 0);
          acc[1][tt] = __builtin_amdgcn_mfma_f32_16x16x32_bf16(af[1][kc], bf, acc[1][tt], 0, 0, 0);
        }
      }
    }
    #pragma unroll
    for (int rt = 0; rt < 2; ++rt){
      float4 b4 = *(const float4*)&qb[sec*256 + h*32 + rt*16 + quad*4];
      #pragma unroll
      for (int tt = 0; tt < 4; ++tt){
        w[rt][tt][0] = (u32)f2bf(acc[rt][tt][0] + b4.x) |
                       ((u32)f2bf(acc[rt][tt][1] + b4.y) << 16);
        w[rt][tt][1] = (u32)f2bf(acc[rt][tt][2] + b4.z) |
                       ((u32)f2bf(acc[rt][tt][3] + b4.w) << 16);
      }
    }
  };

  // D-layout -> [tok][d] bounce, one 16-token quarter at a time (1280 B).
  auto bounce_td = [&](const u32 (&w)[2][4][2], bf16x8 (&frag)[4]){
    #pragma unroll
    for (int tt = 0; tt < 4; ++tt){
      #pragma unroll
      for (int rt = 0; rt < 2; ++rt)
        #pragma unroll
        for (int u = 0; u < 2; ++u)
          *(u32*)&vbw[l16*40 + rt*16 + quad*4 + 2*u] = w[rt][tt][u];
      frag[tt] = *(const bf16x8*)&vbw[l16*40 + quad*8];
    }
  };

  // ---- q, k GEMMs -> register fragments ----
  bf16x8 qf[4], ka[4];
  {
    u32 wq[2][4][2];
    run_gemm(0, wq);
    bounce_td(wq, qf);
  }
  {
    u32 wk[2][4][2];
    run_gemm(1, wk);
    bounce_td(wk, ka);
  }

  // ---- QK^T + softmax + P (per query-tile), bounce to A-layout pa ----
  bf16x8 pa[4][2];
  #pragma unroll
  for (int qt = 0; qt < 4; ++qt){
    f32x4 st[4];
    #pragma unroll
    for (int kt = 0; kt < 4; ++kt)
      st[kt] = __builtin_amdgcn_mfma_f32_16x16x32_bf16(ka[kt], qf[qt], zero4, 0, 0, 0);
    float4 bq[4];
    #pragma unroll
    for (int kt = 0; kt < 4; ++kt)
      bq[kt] = *(const float4*)&biasQ[(h<<12) + (qt*16 + l16)*64 + kt*16 + quad*4];
    float sc[16], mx = -1e30f;
    #pragma unroll
    for (int kt = 0; kt < 4; ++kt)
      #pragma unroll
      for (int r = 0; r < 4; ++r){
        const float v = st[kt][r]*SCALE + ((const float*)&bq[kt])[r];
        sc[kt*4+r] = v; mx = fmaxf(mx, v);
      }
    mx = fmaxf(mx, __shfl_xor(mx, 16));
    mx = fmaxf(mx, __shfl_xor(mx, 32));
    float sum = 0.f;
    #pragma unroll
    for (int i = 0; i < 16; ++i){ sc[i] = __expf(sc[i] - mx); sum += sc[i]; }
    sum += __shfl_xor(sum, 16);
    sum += __shfl_xor(sum, 32);
    const float inv = 1.f / sum;
    #pragma unroll
    for (int kt = 0; kt < 4; ++kt){
      u32 w0 = (u32)f2bf(sc[kt*4+0]*inv) | ((u32)f2bf(sc[kt*4+1]*inv) << 16);
      u32 w1 = (u32)f2bf(sc[kt*4+2]*inv) | ((u32)f2bf(sc[kt*4+3]*inv) << 16);
      *(u32*)&vbw[l16*72 + kt*16 + quad*4 + 0] = w0;
      *(u32*)&vbw[l16*72 + kt*16 + quad*4 + 2] = w1;
    }
    pa[qt][0] = *(const bf16x8*)&vbw[l16*72 +  0 + quad*8];
    pa[qt][1] = *(const bf16x8*)&vbw[l16*72 + 32 + quad*8];
  }

  // ---- v GEMM -> two 16-d half bounces [16 d][72 tok] + split V store ----
  bf16x8 bv[2][2];
  {
    u32 wv[2][4][2];
    run_gemm(2, wv);
    #pragma unroll
    for (int rt = 0; rt < 2; ++rt){
      #pragma unroll
      for (int tt = 0; tt < 4; ++tt)
        #pragma unroll
        for (int u = 0; u < 2; ++u){
          vbw[(quad*4 + 2*u + 0)*72 + tt*16 + l16] = (u16)(wv[rt][tt][u] & 0xFFFFu);
          vbw[(quad*4 + 2*u + 1)*72 + tt*16 + l16] = (u16)(wv[rt][tt][u] >> 16);
        }
      #pragma unroll
      for (int kh = 0; kh < 2; ++kh)
        bv[rt][kh] = *(const bf16x8*)&vbw[l16*72 + kh*32 + quad*8];
      const int dl = lane >> 2;            // 0..15 local d
      #pragma unroll
      for (int j = 0; j < 2; ++j){
        const int ch = (lane & 3)*2 + j;
        u16x8 v8 = *(const u16x8*)&vbw[dl*72 + ch*8];
        *(u16x8*)&vout[((size_t)(b*256 + h*32 + rt*16 + dl))*4096
                       + (size_t)(wy*8 + ch)*64 + wx*8] = v8;
      }
    }
  }

  // ---- PV + direct normalized O store ----
  #pragma unroll
  for (int qt = 0; qt < 4; ++qt){
    #pragma unroll
    for (int dt = 0; dt < 2; ++dt){
      f32x4 o = __builtin_amdgcn_mfma_f32_16x16x32_bf16(pa[qt][0], bv[dt][0], zero4, 0, 0, 0);
      o = __builtin_amdgcn_mfma_f32_16x16x32_bf16(pa[qt][1], bv[dt][1], o, 0, 0, 0);
      float4 o4; o4.x = o[0]; o4.y = o[1]; o4.z = o[2]; o4.w = o[3];
      *(float4*)&xout[((size_t)(b*256 + h*32 + dt*16 + l16))*4096
                      + (size_t)(wy*8 + qt*2 + (quad>>1))*64 + wx*8 + (quad&1)*4] = o4;
    }
  }
}

// ---------------------------------------------------------------------------
// Kernel 4 (fused): depthwise 7x7 + residual + proj GEMM, per image row.
// Block = (b, y), 256 thr. Loop over 8 channel-eighths (32 ch each):
//   stage v rows y-3..y+3 (zero halo, pad L=4) + io row + dw weights -> LDS
//   thread (ch, 8 px): 392-FMA pe in registers + residual -> ts[n][c] bf16
// then the proj MFMA GEMM (identical to old k_proj) on ts, in-place io write.
// LDS: vs 32256 + rb 9216 + wl 6272 + ts 33792 = 81536 -> 2 blocks/CU.
// Eliminates k_dwconv and the 128 MB io round-trip.
// ---------------------------------------------------------------------------
__global__ __launch_bounds__(256) void k_dwproj(
    const u16* __restrict__ vimg, const float* __restrict__ dww,
    const u16* __restrict__ pwb, const float* __restrict__ pb,
    float* __restrict__ io){
  const int row = blockIdx.x;           // b*64 + y
  const int b = row >> 6, y = row & 63;
  __shared__ __align__(16) char smem[81536];
  u16*   vs = (u16*)(smem);             // [32 ch][7 rows][72 px], data @ col 4
  float* rb = (float*)(smem + 32256);   // [32 ch][72] io row
  float* wl = (float*)(smem + 41472);   // [32 ch][49] dw weights
  u16*   ts = (u16*)(smem + 47744);     // [64 px][264 c]
  const int tid = threadIdx.x;

  // zero vs once: halo cols stay 0 forever (stage writes only cols 4..67)
  for (int i = tid; i < 2016; i += 256)
    *(float4*)&vs[i*8] = (float4){0.f, 0.f, 0.f, 0.f};
  __syncthreads();

  const size_t iobase = (size_t)b*256*4096 + (size_t)y*64;

  for (int e = 0; e < 8; ++e){
    const int cg = e*32;
    // ---- stage v (7 rows x 32 ch, coalesced), io row, weights ----
    for (int i = tid; i < 1792; i += 256){
      const int x8 = i & 7, ch = (i >> 3) & 31, dyi = i >> 8;
      const int ry = y + dyi - 3;
      u16x8 v8 = {0,0,0,0,0,0,0,0};
      if (ry >= 0 && ry < 64)
        v8 = *(const u16x8*)&vimg[((size_t)(b*256 + cg + ch))*4096 + ry*64 + x8*8];
      u16* dst = &vs[ch*504 + dyi*72 + 4 + x8*8];
      *(ushort4*)&dst[0] = (ushort4){v8[0], v8[1], v8[2], v8[3]};
      *(ushort4*)&dst[4] = (ushort4){v8[4], v8[5], v8[6], v8[7]};
    }
    for (int i = tid; i < 512; i += 256){
      const int ch = i >> 4, x4 = i & 15;
      float4 f4 = *(const float4*)&io[iobase + (size_t)(cg + ch)*4096 + x4*4];
      *(float4*)&rb[ch*72 + x4*4] = f4;
    }
    for (int i = tid; i < 392; i += 256){
      float4 f4 = *(const float4*)&dww[cg*49 + i*4];
      *(float4*)&wl[i*4] = f4;
    }
    __syncthreads();

    // ---- compute pe (1 ch x 8 px per thread) + residual -> ts ----
    {
      const int ch = tid & 31, x0 = (tid >> 5) * 8;
      float w[49];
      #pragma unroll
      for (int j = 0; j < 49; ++j) w[j] = wl[ch*49 + j];
      float acc[8];
      #pragma unroll
      for (int i = 0; i < 8; ++i) acc[i] = 0.f;
      #pragma unroll
      for (int dy = 0; dy < 7; ++dy){
        const u16* vp = &vs[ch*504 + dy*72 + x0];   // cols x0 .. x0+15
        float r[16];
        #pragma unroll
        for (int k = 0; k < 8; ++k){
          u32 pr = *(const u32*)&vp[2*k];
          r[2*k]   = bf2f((u16)(pr & 0xFFFFu));
          r[2*k+1] = bf2f((u16)(pr >> 16));
        }
        #pragma unroll
        for (int dx = 0; dx < 7; ++dx)
          #pragma unroll
          for (int i = 0; i < 8; ++i)
            acc[i] += w[dy*7 + dx] * r[i + dx + 1];
      }
      float4 i0 = *(const float4*)&rb[ch*72 + x0];
      float4 i1 = *(const float4*)&rb[ch*72 + x0 + 4];
      const int c = cg + ch;
      ts[(x0+0)*264 + c] = f2bf(acc[0] + i0.x);
      ts[(x0+1)*264 + c] = f2bf(acc[1] + i0.y);
      ts[(x0+2)*264 + c] = f2bf(acc[2] + i0.z);
      ts[(x0+3)*264 + c] = f2bf(acc[3] + i0.w);
      ts[(x0+4)*264 + c] = f2bf(acc[4] + i1.x);
      ts[(x0+5)*264 + c] = f2bf(acc[5] + i1.y);
      ts[(x0+6)*264 + c] = f2bf(acc[6] + i1.z);
      ts[(x0+7)*264 + c] = f2bf(acc[7] + i1.w);
    }
    __syncthreads();   // protect vs/rb/wl before next eighth overwrites
  }

  // ---- proj GEMM on ts, in-place io write ----
  const int wave = tid >> 6, lane = tid & 63;
  const int quad = lane >> 4, l16 = lane & 15;
  const f32x4 zero4 = {0.f, 0.f, 0.f, 0.f};
  #pragma unroll
  for (int op = 0; op < 2; ++op){        // o-tile pairs
    bf16x8 af2[2][8];
    #pragma unroll
    for (int oj = 0; oj < 2; ++oj){
      const int orow = (wave*4 + op*2 + oj)*16 + l16;
      #pragma unroll
      for (int kc = 0; kc < 8; ++kc)
        af2[oj][kc] = *(const bf16x8*)(pwb + (size_t)orow*256 + kc*32 + quad*8);
    }
    f32x4 acc[2][4];
    #pragma unroll
    for (int oj = 0; oj < 2; ++oj)
      #pragma unroll
      for (int nt = 0; nt < 4; ++nt) acc[oj][nt] = zero4;
    #pragma unroll
    for (int kc = 0; kc < 8; ++kc){
      bf16x8 bf[4];
      #pragma unroll
      for (int nt = 0; nt < 4; ++nt)
        bf[nt] = *(const bf16x8*)&ts[(nt*16 + l16)*264 + kc*32 + quad*8];
      #pragma unroll
      for (int oj = 0; oj < 2; ++oj)
        #pragma unroll
        for (int nt = 0; nt < 4; ++nt)
          acc[oj][nt] = __builtin_amdgcn_mfma_f32_16x16x32_bf16(af2[oj][kc], bf[nt], acc[oj][nt], 0, 0, 0);
    }
    #pragma unroll
    for (int oj = 0; oj < 2; ++oj){
      const int ot = wave*4 + op*2 + oj;
      #pragma unroll
      for (int nt = 0; nt < 4; ++nt)
        #pragma unroll
        for (int r = 0; r < 4; ++r){
          const int o = ot*16 + quad*4 + r;
          io[((size_t)(b*256 + o))*4096 + (size_t)y*64 + nt*16 + l16] = acc[oj][nt][r] + pb[o];
        }
    }
  }
}

// ---------------------------------------------------------------------------
extern "C" void kernel_launch(void* const* d_in, const int* in_sizes, int n_in,
                              void* d_out, int out_size, void* d_ws, size_t ws_size,
                              hipStream_t stream){
  const float* x   = (const float*)d_in[0];
  const float* qw  = (const float*)d_in[1];
  const float* qb  = (const float*)d_in[2];
  const float* pw  = (const float*)d_in[3];
  const float* pb  = (const float*)d_in[4];
  const float* w1  = (const float*)d_in[5];
  const float* b1  = (const float*)d_in[6];
  const float* w2  = (const float*)d_in[7];
  const float* dww = (const float*)d_in[8];

  // ws: tab 8KB | biasQ 128KB | qwb 384KB | pwb 128KB | vimg 32MB (~34.2 MB)
  char* ws = (char*)d_ws;
  float* tab   = (float*)(ws);
  float* biasQ = (float*)(ws + 8192);
  u16*   qwb   = (u16*)  (ws + 139264);
  u16*   pwb   = (u16*)  (ws + 532480);
  u16*   vimg  = (u16*)  (ws + 663552);
  float* out   = (float*)d_out;          // doubles as attn-out intermediate

  k_cvt_w      <<<1024, 256, 0, stream>>>(qw, pw, qwb, pwb);
  k_cpb_mlp    <<<225,  256, 0, stream>>>(w1, b1, w2, tab);
  k_bias_expand<<<128,  256, 0, stream>>>(tab, biasQ);
  k_qkv_attn   <<<1024, 512, 0, stream>>>(x, qwb, qb, biasQ, out, vimg);
  k_dwproj     <<<1024, 256, 0, stream>>>(vimg, dww, pwb, pb, out);
}

// Round 5
// 317.268 us; speedup vs baseline: 1.0853x; 1.0853x over previous
//
#include <hip/hip_runtime.h>
#include <cstdint>
#include <cstddef>

typedef unsigned short u16;
typedef unsigned int   u32;

#define LW     15
#define BNS    0.9999950000374997f   /* 1/sqrt(1+1e-5) */
#define SCALE  0.17677669529663687f  /* 1/sqrt(32) */

typedef __bf16 bf16x8 __attribute__((ext_vector_type(8)));
typedef float  f32x4  __attribute__((ext_vector_type(4)));
typedef u16    u16x8  __attribute__((ext_vector_type(8)));

__device__ __forceinline__ u16 f2bf(float f){
  union { float f; u32 i; } v; v.f = f;
  u32 r = v.i + 0x7FFFu + ((v.i >> 16) & 1u);
  return (u16)(r >> 16);
}
__device__ __forceinline__ float bf2f(u16 u){
  union { u32 i; float f; } v; v.i = ((u32)u) << 16; return v.f;
}

// ---------------------------------------------------------------------------
// Kernel 0: convert qkv_w (196608) and proj_w (65536) fp32 -> bf16 in ws
// ---------------------------------------------------------------------------
__global__ void k_cvt_w(const float* __restrict__ qw, const float* __restrict__ pw,
                        u16* __restrict__ qwb, u16* __restrict__ pwb){
  const int i = blockIdx.x*256 + threadIdx.x;
  if (i < 196608) qwb[i] = f2bf(qw[i]);
  else            pwb[i - 196608] = f2bf(pw[i - 196608]);
}

// ---------------------------------------------------------------------------
// Kernel 1: CPB MLP -> tab[225][8] fp32
// ---------------------------------------------------------------------------
__global__ void k_cpb_mlp(const float* __restrict__ w1, const float* __restrict__ b1,
                          const float* __restrict__ w2, float* __restrict__ tab){
  const int e = blockIdx.x;        // 0..224
  const int c = threadIdx.x;       // 0..255
  const float a0 = (float)(e / LW - 7);
  const float a1 = (float)(e % LW - 7);
  const float cx = copysignf(log2f(fabsf(a0)*(8.f/7.f) + 1.f) * (1.f/3.f), a0);
  const float cy = copysignf(log2f(fabsf(a1)*(8.f/7.f) + 1.f) * (1.f/3.f), a1);
  float pre = (cx*w1[2*c] + cy*w1[2*c+1] + b1[c]) * BNS;
  float hid = pre / (1.f + __expf(-pre));   // silu
  __shared__ float hl[256];
  hl[c] = hid;
  __syncthreads();
  if (c < 8){
    float s = 0.f;
    for (int i = 0; i < 256; ++i) s += hl[i] * w2[c*256 + i];
    tab[e*8 + c] = s * BNS;
  }
}

// ---------------------------------------------------------------------------
// Kernel 2: biasQ[h][query q][key] = 16*sigmoid(tab[rpi(q,key)][h])
// ---------------------------------------------------------------------------
__global__ void k_bias_expand(const float* __restrict__ tab, float* __restrict__ biasQ){
  const int id = blockIdx.x*256 + threadIdx.x;   // h*4096 + q*64 + key
  const int key = id & 63;
  const int q   = (id >> 6) & 63;
  const int h   = id >> 12;
  const int dy = (q >> 3) - (key >> 3) + 7;
  const int dx = (q & 7)  - (key & 7)  + 7;
  const float v = tab[(dy*LW + dx)*8 + h];
  biasQ[id] = 16.f / (1.f + __expf(-v));
}

// ---------------------------------------------------------------------------
// Kernel 3: fused qkv GEMM + attention, WAVE-PER-HEAD, ONE barrier.
// R5 ILP restructure of the R3 kernel:
//  - q and k GEMMs MERGED: af[4][4] (4 row-tiles x half-K) preloaded -> 16
//    weight loads in flight, 16 independent MFMA chains per half-K step.
//  - v GEMM: full-K af[2][8] preload (16 loads in flight, 8 chains).
//  - 3 serialized load batches per wave instead of 6.
//  - launch_bounds(512,2): VGPR cap 256 (est ~160-190 -> 2 waves/SIMD,
//    16 waves/CU = 2 blocks/CU, same as the LDS limit).
// Bounce layout as R3 (per-wave 4608 B):
//   q/k: [32 tok][40 d] two halves -> qf[4]/ka[4]
//   P:   [16 q][72 key]            -> pa[qt][2]
//   v:   [32 d][72 tok]            -> bv[2][2] + coalesced V store
// LDS: xs 33792 + 8*4608 = 70656 -> 2 blocks/CU.
// ---------------------------------------------------------------------------
__global__ __launch_bounds__(512, 2) void k_qkv_attn(
    const float* __restrict__ x, const u16* __restrict__ qwb,
    const float* __restrict__ qb, const float* __restrict__ biasQ,
    float* __restrict__ xout, u16* __restrict__ vout){
  const int win = blockIdx.x;
  const int b = win >> 6, wy = (win >> 3) & 7, wx = win & 7;
  __shared__ __align__(16) char smem[70656];
  u16* xs = (u16*)smem;                              // [64 tok][264 c]
  const int tid  = threadIdx.x;
  const int wave = tid >> 6, lane = tid & 63;
  const int quad = lane >> 4, l16 = lane & 15;
  u16* vbw = (u16*)(smem + 33792 + wave*4608);       // per-wave bounce

  // ---- stage x -> xs bf16 [tok][c] ----
  const float* xbase = x + (size_t)b*256*4096 + (size_t)(wy*8)*64 + wx*8;
  for (int i = tid; i < 4096; i += 512){
    const int c  = i >> 4;
    const int g  = i & 15;
    const int py = g >> 1, xh = (g & 1) * 4;
    float4 v4 = *(const float4*)&xbase[(size_t)c*4096 + py*64 + xh];
    const int n0 = py*8 + xh;
    xs[(n0+0)*264 + c] = f2bf(v4.x);
    xs[(n0+1)*264 + c] = f2bf(v4.y);
    xs[(n0+2)*264 + c] = f2bf(v4.z);
    xs[(n0+3)*264 + c] = f2bf(v4.w);
  }
  __syncthreads();   // the ONLY barrier

  const int h = wave;
  const f32x4 zero4 = {0.f, 0.f, 0.f, 0.f};

  // D-layout -> [tok][d] bounce (two 32-token halves), read back as frags.
  auto bounce_td = [&](const u32 (&w)[2][4][2], bf16x8 (&frag)[4]){
    #pragma unroll
    for (int half = 0; half < 2; ++half){
      #pragma unroll
      for (int t2 = 0; t2 < 2; ++t2){     // tt = half*2 + t2
        const int tt = half*2 + t2;
        #pragma unroll
        for (int rt = 0; rt < 2; ++rt)
          #pragma unroll
          for (int u = 0; u < 2; ++u)
            *(u32*)&vbw[(t2*16 + l16)*40 + rt*16 + quad*4 + 2*u] = w[rt][tt][u];
      }
      #pragma unroll
      for (int t2 = 0; t2 < 2; ++t2)
        frag[half*2 + t2] = *(const bf16x8*)&vbw[(t2*16 + l16)*40 + quad*8];
    }
  };

  // ---- combined q+k GEMM: 4 row-tiles x 4 token-tiles, K=256 ----
  // row-tile rt4: 0=q.lo 1=q.hi 2=k.lo 3=k.hi
  u32 wq[2][4][2], wk[2][4][2];
  {
    f32x4 acc[4][4];
    #pragma unroll
    for (int r4 = 0; r4 < 4; ++r4)
      #pragma unroll
      for (int tt = 0; tt < 4; ++tt) acc[r4][tt] = zero4;
    #pragma unroll
    for (int kh2 = 0; kh2 < 2; ++kh2){
      bf16x8 af[4][4];        // 16 loads issued together
      #pragma unroll
      for (int r4 = 0; r4 < 4; ++r4){
        const int sec = r4 >> 1, rtl = r4 & 1;
        const int wr = sec*256 + h*32 + rtl*16 + l16;
        #pragma unroll
        for (int kc = 0; kc < 4; ++kc)
          af[r4][kc] = *(const bf16x8*)(qwb + (size_t)wr*256 + (kh2*4 + kc)*32 + quad*8);
      }
      #pragma unroll
      for (int kc = 0; kc < 4; ++kc){
        #pragma unroll
        for (int tt = 0; tt < 4; ++tt){
          bf16x8 bf = *(const bf16x8*)&xs[(tt*16 + l16)*264 + (kh2*4 + kc)*32 + quad*8];
          #pragma unroll
          for (int r4 = 0; r4 < 4; ++r4)
            acc[r4][tt] = __builtin_amdgcn_mfma_f32_16x16x32_bf16(af[r4][kc], bf, acc[r4][tt], 0, 0, 0);
        }
      }
    }
    #pragma unroll
    for (int rt = 0; rt < 2; ++rt){
      float4 bq4 = *(const float4*)&qb[      h*32 + rt*16 + quad*4];
      float4 bk4 = *(const float4*)&qb[256 + h*32 + rt*16 + quad*4];
      #pragma unroll
      for (int tt = 0; tt < 4; ++tt){
        wq[rt][tt][0] = (u32)f2bf(acc[rt][tt][0] + bq4.x) |
                        ((u32)f2bf(acc[rt][tt][1] + bq4.y) << 16);
        wq[rt][tt][1] = (u32)f2bf(acc[rt][tt][2] + bq4.z) |
                        ((u32)f2bf(acc[rt][tt][3] + bq4.w) << 16);
        wk[rt][tt][0] = (u32)f2bf(acc[2+rt][tt][0] + bk4.x) |
                        ((u32)f2bf(acc[2+rt][tt][1] + bk4.y) << 16);
        wk[rt][tt][1] = (u32)f2bf(acc[2+rt][tt][2] + bk4.z) |
                        ((u32)f2bf(acc[2+rt][tt][3] + bk4.w) << 16);
      }
    }
  }
  bf16x8 qf[4], ka[4];
  bounce_td(wq, qf);
  bounce_td(wk, ka);

  // ---- QK^T + softmax + P (per query-tile), bounce to A-layout pa ----
  bf16x8 pa[4][2];
  #pragma unroll
  for (int qt = 0; qt < 4; ++qt){
    f32x4 st[4];
    #pragma unroll
    for (int kt = 0; kt < 4; ++kt)
      st[kt] = __builtin_amdgcn_mfma_f32_16x16x32_bf16(ka[kt], qf[qt], zero4, 0, 0, 0);
    float4 bq[4];
    #pragma unroll
    for (int kt = 0; kt < 4; ++kt)
      bq[kt] = *(const float4*)&biasQ[(h<<12) + (qt*16 + l16)*64 + kt*16 + quad*4];
    float sc[16], mx = -1e30f;
    #pragma unroll
    for (int kt = 0; kt < 4; ++kt)
      #pragma unroll
      for (int r = 0; r < 4; ++r){
        const float v = st[kt][r]*SCALE + ((const float*)&bq[kt])[r];
        sc[kt*4+r] = v; mx = fmaxf(mx, v);
      }
    mx = fmaxf(mx, __shfl_xor(mx, 16));
    mx = fmaxf(mx, __shfl_xor(mx, 32));
    float sum = 0.f;
    #pragma unroll
    for (int i = 0; i < 16; ++i){ sc[i] = __expf(sc[i] - mx); sum += sc[i]; }
    sum += __shfl_xor(sum, 16);
    sum += __shfl_xor(sum, 32);
    const float inv = 1.f / sum;
    #pragma unroll
    for (int kt = 0; kt < 4; ++kt){
      u32 w0 = (u32)f2bf(sc[kt*4+0]*inv) | ((u32)f2bf(sc[kt*4+1]*inv) << 16);
      u32 w1 = (u32)f2bf(sc[kt*4+2]*inv) | ((u32)f2bf(sc[kt*4+3]*inv) << 16);
      *(u32*)&vbw[l16*72 + kt*16 + quad*4 + 0] = w0;
      *(u32*)&vbw[l16*72 + kt*16 + quad*4 + 2] = w1;
    }
    pa[qt][0] = *(const bf16x8*)&vbw[l16*72 +  0 + quad*8];
    pa[qt][1] = *(const bf16x8*)&vbw[l16*72 + 32 + quad*8];
  }

  // ---- v GEMM (full-K af preload, 16 loads in flight, 8 chains) ----
  {
    bf16x8 afv[2][8];
    #pragma unroll
    for (int rt = 0; rt < 2; ++rt){
      const int wr = 512 + h*32 + rt*16 + l16;
      #pragma unroll
      for (int kc = 0; kc < 8; ++kc)
        afv[rt][kc] = *(const bf16x8*)(qwb + (size_t)wr*256 + kc*32 + quad*8);
    }
    f32x4 accv[2][4];
    #pragma unroll
    for (int rt = 0; rt < 2; ++rt)
      #pragma unroll
      for (int tt = 0; tt < 4; ++tt) accv[rt][tt] = zero4;
    #pragma unroll
    for (int kc = 0; kc < 8; ++kc){
      #pragma unroll
      for (int tt = 0; tt < 4; ++tt){
        bf16x8 bf = *(const bf16x8*)&xs[(tt*16 + l16)*264 + kc*32 + quad*8];
        accv[0][tt] = __builtin_amdgcn_mfma_f32_16x16x32_bf16(afv[0][kc], bf, accv[0][tt], 0, 0, 0);
        accv[1][tt] = __builtin_amdgcn_mfma_f32_16x16x32_bf16(afv[1][kc], bf, accv[1][tt], 0, 0, 0);
      }
    }
    // pack + transposed bounce [32 d][72 tok]
    #pragma unroll
    for (int rt = 0; rt < 2; ++rt){
      float4 b4 = *(const float4*)&qb[512 + h*32 + rt*16 + quad*4];
      #pragma unroll
      for (int tt = 0; tt < 4; ++tt){
        vbw[(rt*16 + quad*4 + 0)*72 + tt*16 + l16] = f2bf(accv[rt][tt][0] + b4.x);
        vbw[(rt*16 + quad*4 + 1)*72 + tt*16 + l16] = f2bf(accv[rt][tt][1] + b4.y);
        vbw[(rt*16 + quad*4 + 2)*72 + tt*16 + l16] = f2bf(accv[rt][tt][2] + b4.z);
        vbw[(rt*16 + quad*4 + 3)*72 + tt*16 + l16] = f2bf(accv[rt][tt][3] + b4.w);
      }
    }
  }
  bf16x8 bv[2][2];
  #pragma unroll
  for (int dt = 0; dt < 2; ++dt)
    #pragma unroll
    for (int kh = 0; kh < 2; ++kh)
      bv[dt][kh] = *(const bf16x8*)&vbw[(dt*16 + l16)*72 + kh*32 + quad*8];

  // ---- V global store (bf16 image layout), coalesced u16x8 ----
  {
    const int d  = lane >> 1;
    #pragma unroll
    for (int i = 0; i < 4; ++i){
      const int ch = (lane & 1)*4 + i;
      u16x8 v8 = *(const u16x8*)&vbw[d*72 + ch*8];
      *(u16x8*)&vout[((size_t)(b*256 + h*32 + d))*4096 + (size_t)(wy*8 + ch)*64 + wx*8] = v8;
    }
  }

  // ---- PV + direct normalized O store ----
  #pragma unroll
  for (int qt = 0; qt < 4; ++qt){
    #pragma unroll
    for (int dt = 0; dt < 2; ++dt){
      f32x4 o = __builtin_amdgcn_mfma_f32_16x16x32_bf16(pa[qt][0], bv[dt][0], zero4, 0, 0, 0);
      o = __builtin_amdgcn_mfma_f32_16x16x32_bf16(pa[qt][1], bv[dt][1], o, 0, 0, 0);
      float4 o4; o4.x = o[0]; o4.y = o[1]; o4.z = o[2]; o4.w = o[3];
      *(float4*)&xout[((size_t)(b*256 + h*32 + dt*16 + l16))*4096
                      + (size_t)(wy*8 + qt*2 + (quad>>1))*64 + wx*8 + (quad&1)*4] = o4;
    }
  }
}

// ---------------------------------------------------------------------------
// Kernel 4: depthwise 7x7 + residual, IN PLACE on io (fp32).
// Register-blocked 4x4 outputs; staging vectorized (u16x8 loads).
// ---------------------------------------------------------------------------
__global__ __launch_bounds__(256) void k_dwconv(
    const u16* __restrict__ vimg, const float* __restrict__ dww,
    float* __restrict__ io){
  const int b = blockIdx.x >> 8, c = blockIdx.x & 255;
  __shared__ float tile[70*72];   // zero-padded halo
  const size_t base = ((size_t)(b*256 + c)) * 4096;
  for (int i = threadIdx.x; i < 1260; i += 256)
    *(float4*)&tile[i*4] = (float4){0.f, 0.f, 0.f, 0.f};
  float w[49];
  #pragma unroll
  for (int j = 0; j < 49; ++j) w[j] = dww[c*49 + j];
  __syncthreads();
  for (int i = threadIdx.x; i < 512; i += 256){
    const int y = i >> 3, x8 = (i & 7) * 8;
    u16x8 v = *(const u16x8*)&vimg[base + y*64 + x8];
    #pragma unroll
    for (int j = 0; j < 8; ++j) tile[(y+3)*72 + x8 + 3 + j] = bf2f(v[j]);
  }
  __syncthreads();

  const int x0 = (threadIdx.x & 15) * 4;
  const int y0 = (threadIdx.x >> 4) * 4;
  float acc[4][4];
  #pragma unroll
  for (int i = 0; i < 4; ++i)
    #pragma unroll
    for (int j = 0; j < 4; ++j) acc[i][j] = 0.f;

  #pragma unroll
  for (int ty = 0; ty < 10; ++ty){
    const float* rp = &tile[(y0 + ty)*72 + x0];
    float r[12];
    *(float4*)&r[0] = *(const float4*)&rp[0];
    *(float4*)&r[4] = *(const float4*)&rp[4];
    *(float4*)&r[8] = *(const float4*)&rp[8];
    #pragma unroll
    for (int oy = 0; oy < 4; ++oy){
      if (ty >= oy && ty - oy <= 6){
        const int ky = ty - oy;
        #pragma unroll
        for (int ox = 0; ox < 4; ++ox)
          #pragma unroll
          for (int kx = 0; kx < 7; ++kx)
            acc[oy][ox] += w[ky*7 + kx] * r[ox + kx];
      }
    }
  }
  #pragma unroll
  for (int oy = 0; oy < 4; ++oy){
    const size_t gi = base + (size_t)(y0 + oy)*64 + x0;
    float4 res = *(const float4*)&io[gi];
    res.x += acc[oy][0]; res.y += acc[oy][1];
    res.z += acc[oy][2]; res.w += acc[oy][3];
    *(float4*)&io[gi] = res;
  }
}

// ---------------------------------------------------------------------------
// Kernel 5: proj GEMM per image row (MFMA), IN PLACE on io fp32.
// o-tile pairs with af in regs, kc-outer, 8 independent chains; float4 staging.
// ---------------------------------------------------------------------------
__global__ __launch_bounds__(256) void k_proj(
    const u16* __restrict__ pwb, const float* __restrict__ pb,
    float* __restrict__ io){
  const int row = blockIdx.x;           // b*64 + y
  const int b = row >> 6, y = row & 63;
  __shared__ __align__(16) u16 ts[64*264];   // [pixel n][c] bf16, pad +8
  const float* tbase = io + (size_t)b*256*4096 + (size_t)y*64;
  for (int i = threadIdx.x; i < 4096; i += 256){
    const int c = i >> 4, n0 = (i & 15) * 4;
    float4 v4 = *(const float4*)&tbase[(size_t)c*4096 + n0];
    ts[(n0+0)*264 + c] = f2bf(v4.x);
    ts[(n0+1)*264 + c] = f2bf(v4.y);
    ts[(n0+2)*264 + c] = f2bf(v4.z);
    ts[(n0+3)*264 + c] = f2bf(v4.w);
  }
  __syncthreads();
  const int wave = threadIdx.x >> 6, lane = threadIdx.x & 63;
  const int quad = lane >> 4, l16 = lane & 15;
  const f32x4 zero4 = {0.f, 0.f, 0.f, 0.f};
  #pragma unroll
  for (int op = 0; op < 2; ++op){        // o-tile pairs
    bf16x8 af2[2][8];
    #pragma unroll
    for (int oj = 0; oj < 2; ++oj){
      const int orow = (wave*4 + op*2 + oj)*16 + l16;
      #pragma unroll
      for (int kc = 0; kc < 8; ++kc)
        af2[oj][kc] = *(const bf16x8*)(pwb + (size_t)orow*256 + kc*32 + quad*8);
    }
    f32x4 acc[2][4];
    #pragma unroll
    for (int oj = 0; oj < 2; ++oj)
      #pragma unroll
      for (int nt = 0; nt < 4; ++nt) acc[oj][nt] = zero4;
    #pragma unroll
    for (int kc = 0; kc < 8; ++kc){
      bf16x8 bf[4];
      #pragma unroll
      for (int nt = 0; nt < 4; ++nt)
        bf[nt] = *(const bf16x8*)&ts[(nt*16 + l16)*264 + kc*32 + quad*8];
      #pragma unroll
      for (int oj = 0; oj < 2; ++oj)
        #pragma unroll
        for (int nt = 0; nt < 4; ++nt)
          acc[oj][nt] = __builtin_amdgcn_mfma_f32_16x16x32_bf16(af2[oj][kc], bf[nt], acc[oj][nt], 0, 0, 0);
    }
    #pragma unroll
    for (int oj = 0; oj < 2; ++oj){
      const int ot = wave*4 + op*2 + oj;
      #pragma unroll
      for (int nt = 0; nt < 4; ++nt)
        #pragma unroll
        for (int r = 0; r < 4; ++r){
          const int o = ot*16 + quad*4 + r;
          io[((size_t)(b*256 + o))*4096 + (size_t)y*64 + nt*16 + l16] = acc[oj][nt][r] + pb[o];
        }
    }
  }
}

// ---------------------------------------------------------------------------
extern "C" void kernel_launch(void* const* d_in, const int* in_sizes, int n_in,
                              void* d_out, int out_size, void* d_ws, size_t ws_size,
                              hipStream_t stream){
  const float* x   = (const float*)d_in[0];
  const float* qw  = (const float*)d_in[1];
  const float* qb  = (const float*)d_in[2];
  const float* pw  = (const float*)d_in[3];
  const float* pb  = (const float*)d_in[4];
  const float* w1  = (const float*)d_in[5];
  const float* b1  = (const float*)d_in[6];
  const float* w2  = (const float*)d_in[7];
  const float* dww = (const float*)d_in[8];

  // ws: tab 8KB | biasQ 128KB | qwb 384KB | pwb 128KB | vimg 32MB (~34.2 MB)
  char* ws = (char*)d_ws;
  float* tab   = (float*)(ws);
  float* biasQ = (float*)(ws + 8192);
  u16*   qwb   = (u16*)  (ws + 139264);
  u16*   pwb   = (u16*)  (ws + 532480);
  u16*   vimg  = (u16*)  (ws + 663552);
  float* out   = (float*)d_out;          // doubles as attn-out intermediate

  k_cvt_w      <<<1024, 256, 0, stream>>>(qw, pw, qwb, pwb);
  k_cpb_mlp    <<<225,  256, 0, stream>>>(w1, b1, w2, tab);
  k_bias_expand<<<128,  256, 0, stream>>>(tab, biasQ);
  k_qkv_attn   <<<1024, 512, 0, stream>>>(x, qwb, qb, biasQ, out, vimg);
  k_dwconv     <<<4096, 256, 0, stream>>>(vimg, dww, out);
  k_proj       <<<1024, 256, 0, stream>>>(pwb, pb, out);
}

// Round 6
// 310.083 us; speedup vs baseline: 1.1104x; 1.0232x over previous
//
#include <hip/hip_runtime.h>
#include <cstdint>
#include <cstddef>

typedef unsigned short u16;
typedef unsigned int   u32;

#define LW     15
#define BNS    0.9999950000374997f   /* 1/sqrt(1+1e-5) */
#define SCALE  0.17677669529663687f  /* 1/sqrt(32) */

typedef __bf16 bf16x8 __attribute__((ext_vector_type(8)));
typedef float  f32x4  __attribute__((ext_vector_type(4)));
typedef u16    u16x8  __attribute__((ext_vector_type(8)));

__device__ __forceinline__ u16 f2bf(float f){
  union { float f; u32 i; } v; v.f = f;
  u32 r = v.i + 0x7FFFu + ((v.i >> 16) & 1u);
  return (u16)(r >> 16);
}
__device__ __forceinline__ float bf2f(u16 u){
  union { u32 i; float f; } v; v.i = ((u32)u) << 16; return v.f;
}

// ---------------------------------------------------------------------------
// Kernel 0: convert qkv_w (196608) and proj_w (65536) fp32 -> bf16 in ws
// ---------------------------------------------------------------------------
__global__ void k_cvt_w(const float* __restrict__ qw, const float* __restrict__ pw,
                        u16* __restrict__ qwb, u16* __restrict__ pwb){
  const int i = blockIdx.x*256 + threadIdx.x;
  if (i < 196608) qwb[i] = f2bf(qw[i]);
  else            pwb[i - 196608] = f2bf(pw[i - 196608]);
}

// ---------------------------------------------------------------------------
// Kernel 1: CPB MLP -> tab[225][8] fp32
// ---------------------------------------------------------------------------
__global__ void k_cpb_mlp(const float* __restrict__ w1, const float* __restrict__ b1,
                          const float* __restrict__ w2, float* __restrict__ tab){
  const int e = blockIdx.x;        // 0..224
  const int c = threadIdx.x;       // 0..255
  const float a0 = (float)(e / LW - 7);
  const float a1 = (float)(e % LW - 7);
  const float cx = copysignf(log2f(fabsf(a0)*(8.f/7.f) + 1.f) * (1.f/3.f), a0);
  const float cy = copysignf(log2f(fabsf(a1)*(8.f/7.f) + 1.f) * (1.f/3.f), a1);
  float pre = (cx*w1[2*c] + cy*w1[2*c+1] + b1[c]) * BNS;
  float hid = pre / (1.f + __expf(-pre));   // silu
  __shared__ float hl[256];
  hl[c] = hid;
  __syncthreads();
  if (c < 8){
    float s = 0.f;
    for (int i = 0; i < 256; ++i) s += hl[i] * w2[c*256 + i];
    tab[e*8 + c] = s * BNS;
  }
}

// ---------------------------------------------------------------------------
// Kernel 2: biasQ[h][query q][key] = 16*sigmoid(tab[rpi(q,key)][h])
// ---------------------------------------------------------------------------
__global__ void k_bias_expand(const float* __restrict__ tab, float* __restrict__ biasQ){
  const int id = blockIdx.x*256 + threadIdx.x;   // h*4096 + q*64 + key
  const int key = id & 63;
  const int q   = (id >> 6) & 63;
  const int h   = id >> 12;
  const int dy = (q >> 3) - (key >> 3) + 7;
  const int dx = (q & 7)  - (key & 7)  + 7;
  const float v = tab[(dy*LW + dx)*8 + h];
  biasQ[id] = 16.f / (1.f + __expf(-v));
}

// ---------------------------------------------------------------------------
// Kernel 3: fused qkv GEMM + attention, WAVE-PER-HEAD, ONE barrier.
// R3 dataflow (best measured: 139 us) with per-wave bounce shrunk 4608->2560:
//   q/k: [32 tok][40 d] full two-half bounce (R3 style, NOT quartered)
//   P:   [16 q][72 key] (2304 B)
//   v:   two 16-d halves [16 d][72 tok] (2304 B) + split V store (R4-proven)
// LDS: xs 33792 + 8*2560 = 54272 -> 3 blocks/CU (162816 <= 163840).
// ---------------------------------------------------------------------------
__global__ __launch_bounds__(512, 4) void k_qkv_attn(
    const float* __restrict__ x, const u16* __restrict__ qwb,
    const float* __restrict__ qb, const float* __restrict__ biasQ,
    float* __restrict__ xout, u16* __restrict__ vout){
  const int win = blockIdx.x;
  const int b = win >> 6, wy = (win >> 3) & 7, wx = win & 7;
  __shared__ __align__(16) char smem[54272];
  u16* xs = (u16*)smem;                              // [64 tok][264 c]
  const int tid  = threadIdx.x;
  const int wave = tid >> 6, lane = tid & 63;
  const int quad = lane >> 4, l16 = lane & 15;
  u16* vbw = (u16*)(smem + 33792 + wave*2560);       // per-wave bounce

  // ---- stage x -> xs bf16 [tok][c] ----
  const float* xbase = x + (size_t)b*256*4096 + (size_t)(wy*8)*64 + wx*8;
  for (int i = tid; i < 4096; i += 512){
    const int c  = i >> 4;
    const int g  = i & 15;
    const int py = g >> 1, xh = (g & 1) * 4;
    float4 v4 = *(const float4*)&xbase[(size_t)c*4096 + py*64 + xh];
    const int n0 = py*8 + xh;
    xs[(n0+0)*264 + c] = f2bf(v4.x);
    xs[(n0+1)*264 + c] = f2bf(v4.y);
    xs[(n0+2)*264 + c] = f2bf(v4.z);
    xs[(n0+3)*264 + c] = f2bf(v4.w);
  }
  __syncthreads();   // the ONLY barrier

  const int h = wave;
  const f32x4 zero4 = {0.f, 0.f, 0.f, 0.f};

  // GEMM for one section (0=q,1=k,2=v): 2 row-tiles x 4 token-tiles, K=256.
  auto run_gemm = [&](int sec, u32 (&w)[2][4][2]){
    f32x4 acc[2][4];
    #pragma unroll
    for (int rt = 0; rt < 2; ++rt)
      #pragma unroll
      for (int tt = 0; tt < 4; ++tt) acc[rt][tt] = zero4;
    #pragma unroll
    for (int kh2 = 0; kh2 < 2; ++kh2){
      bf16x8 af[2][4];
      #pragma unroll
      for (int rt = 0; rt < 2; ++rt){
        const int wr = sec*256 + h*32 + rt*16 + l16;
        #pragma unroll
        for (int kc = 0; kc < 4; ++kc)
          af[rt][kc] = *(const bf16x8*)(qwb + (size_t)wr*256 + (kh2*4 + kc)*32 + quad*8);
      }
      #pragma unroll
      for (int kc = 0; kc < 4; ++kc){
        #pragma unroll
        for (int tt = 0; tt < 4; ++tt){
          bf16x8 bf = *(const bf16x8*)&xs[(tt*16 + l16)*264 + (kh2*4 + kc)*32 + quad*8];
          acc[0][tt] = __builtin_amdgcn_mfma_f32_16x16x32_bf16(af[0][kc], bf, acc[0][tt], 0, 0, 0);
          acc[1][tt] = __builtin_amdgcn_mfma_f32_16x16x32_bf16(af[1][kc], bf, acc[1][tt], 0, 0, 0);
        }
      }
    }
    #pragma unroll
    for (int rt = 0; rt < 2; ++rt){
      float4 b4 = *(const float4*)&qb[sec*256 + h*32 + rt*16 + quad*4];
      #pragma unroll
      for (int tt = 0; tt < 4; ++tt){
        w[rt][tt][0] = (u32)f2bf(acc[rt][tt][0] + b4.x) |
                       ((u32)f2bf(acc[rt][tt][1] + b4.y) << 16);
        w[rt][tt][1] = (u32)f2bf(acc[rt][tt][2] + b4.z) |
                       ((u32)f2bf(acc[rt][tt][3] + b4.w) << 16);
      }
    }
  };

  // D-layout -> [tok][d] bounce (two 32-token halves), read back as frags.
  auto bounce_td = [&](const u32 (&w)[2][4][2], bf16x8 (&frag)[4]){
    #pragma unroll
    for (int half = 0; half < 2; ++half){
      #pragma unroll
      for (int t2 = 0; t2 < 2; ++t2){     // tt = half*2 + t2
        const int tt = half*2 + t2;
        #pragma unroll
        for (int rt = 0; rt < 2; ++rt)
          #pragma unroll
          for (int u = 0; u < 2; ++u)
            *(u32*)&vbw[(t2*16 + l16)*40 + rt*16 + quad*4 + 2*u] = w[rt][tt][u];
      }
      #pragma unroll
      for (int t2 = 0; t2 < 2; ++t2)
        frag[half*2 + t2] = *(const bf16x8*)&vbw[(t2*16 + l16)*40 + quad*8];
    }
  };

  // ---- q, k GEMMs -> register fragments ----
  bf16x8 qf[4], ka[4];
  {
    u32 wq[2][4][2];
    run_gemm(0, wq);
    bounce_td(wq, qf);
  }
  {
    u32 wk[2][4][2];
    run_gemm(1, wk);
    bounce_td(wk, ka);
  }

  // ---- QK^T + softmax + P (per query-tile), bounce to A-layout pa ----
  bf16x8 pa[4][2];
  #pragma unroll
  for (int qt = 0; qt < 4; ++qt){
    f32x4 st[4];
    #pragma unroll
    for (int kt = 0; kt < 4; ++kt)
      st[kt] = __builtin_amdgcn_mfma_f32_16x16x32_bf16(ka[kt], qf[qt], zero4, 0, 0, 0);
    float4 bq[4];
    #pragma unroll
    for (int kt = 0; kt < 4; ++kt)
      bq[kt] = *(const float4*)&biasQ[(h<<12) + (qt*16 + l16)*64 + kt*16 + quad*4];
    float sc[16], mx = -1e30f;
    #pragma unroll
    for (int kt = 0; kt < 4; ++kt)
      #pragma unroll
      for (int r = 0; r < 4; ++r){
        const float v = st[kt][r]*SCALE + ((const float*)&bq[kt])[r];
        sc[kt*4+r] = v; mx = fmaxf(mx, v);
      }
    mx = fmaxf(mx, __shfl_xor(mx, 16));
    mx = fmaxf(mx, __shfl_xor(mx, 32));
    float sum = 0.f;
    #pragma unroll
    for (int i = 0; i < 16; ++i){ sc[i] = __expf(sc[i] - mx); sum += sc[i]; }
    sum += __shfl_xor(sum, 16);
    sum += __shfl_xor(sum, 32);
    const float inv = 1.f / sum;
    #pragma unroll
    for (int kt = 0; kt < 4; ++kt){
      u32 w0 = (u32)f2bf(sc[kt*4+0]*inv) | ((u32)f2bf(sc[kt*4+1]*inv) << 16);
      u32 w1 = (u32)f2bf(sc[kt*4+2]*inv) | ((u32)f2bf(sc[kt*4+3]*inv) << 16);
      *(u32*)&vbw[l16*72 + kt*16 + quad*4 + 0] = w0;
      *(u32*)&vbw[l16*72 + kt*16 + quad*4 + 2] = w1;
    }
    pa[qt][0] = *(const bf16x8*)&vbw[l16*72 +  0 + quad*8];
    pa[qt][1] = *(const bf16x8*)&vbw[l16*72 + 32 + quad*8];
  }

  // ---- v GEMM -> two 16-d half bounces [16 d][72 tok] + split V store ----
  bf16x8 bv[2][2];
  {
    u32 wv[2][4][2];
    run_gemm(2, wv);
    #pragma unroll
    for (int rt = 0; rt < 2; ++rt){
      #pragma unroll
      for (int tt = 0; tt < 4; ++tt)
        #pragma unroll
        for (int u = 0; u < 2; ++u){
          vbw[(quad*4 + 2*u + 0)*72 + tt*16 + l16] = (u16)(wv[rt][tt][u] & 0xFFFFu);
          vbw[(quad*4 + 2*u + 1)*72 + tt*16 + l16] = (u16)(wv[rt][tt][u] >> 16);
        }
      #pragma unroll
      for (int kh = 0; kh < 2; ++kh)
        bv[rt][kh] = *(const bf16x8*)&vbw[l16*72 + kh*32 + quad*8];
      const int dl = lane >> 2;            // 0..15 local d
      #pragma unroll
      for (int j = 0; j < 2; ++j){
        const int ch = (lane & 3)*2 + j;
        u16x8 v8 = *(const u16x8*)&vbw[dl*72 + ch*8];
        *(u16x8*)&vout[((size_t)(b*256 + h*32 + rt*16 + dl))*4096
                       + (size_t)(wy*8 + ch)*64 + wx*8] = v8;
      }
    }
  }

  // ---- PV + direct normalized O store ----
  #pragma unroll
  for (int qt = 0; qt < 4; ++qt){
    #pragma unroll
    for (int dt = 0; dt < 2; ++dt){
      f32x4 o = __builtin_amdgcn_mfma_f32_16x16x32_bf16(pa[qt][0], bv[dt][0], zero4, 0, 0, 0);
      o = __builtin_amdgcn_mfma_f32_16x16x32_bf16(pa[qt][1], bv[dt][1], o, 0, 0, 0);
      float4 o4; o4.x = o[0]; o4.y = o[1]; o4.z = o[2]; o4.w = o[3];
      *(float4*)&xout[((size_t)(b*256 + h*32 + dt*16 + l16))*4096
                      + (size_t)(wy*8 + qt*2 + (quad>>1))*64 + wx*8 + (quad&1)*4] = o4;
    }
  }
}

// ---------------------------------------------------------------------------
// Kernel 4: depthwise 7x7 + residual, writes f2bf(O + pe) IN PLACE into vimg.
// io (attn O, fp32) is READ-ONLY here; vimg is fully staged to LDS before
// any write, and each block owns one (b,c) plane -> in-place is safe.
// Traffic: 134 MB (was 167); output is the bf16 proj input directly.
// ---------------------------------------------------------------------------
__global__ __launch_bounds__(256) void k_dwconv(
    const float* __restrict__ io, const float* __restrict__ dww,
    u16* __restrict__ vimg){
  const int b = blockIdx.x >> 8, c = blockIdx.x & 255;
  __shared__ float tile[70*72];   // zero-padded halo
  const size_t base = ((size_t)(b*256 + c)) * 4096;
  for (int i = threadIdx.x; i < 1260; i += 256)
    *(float4*)&tile[i*4] = (float4){0.f, 0.f, 0.f, 0.f};
  float w[49];
  #pragma unroll
  for (int j = 0; j < 49; ++j) w[j] = dww[c*49 + j];
  __syncthreads();
  for (int i = threadIdx.x; i < 512; i += 256){
    const int y = i >> 3, x8 = (i & 7) * 8;
    u16x8 v = *(const u16x8*)&vimg[base + y*64 + x8];
    #pragma unroll
    for (int j = 0; j < 8; ++j) tile[(y+3)*72 + x8 + 3 + j] = bf2f(v[j]);
  }
  __syncthreads();

  const int x0 = (threadIdx.x & 15) * 4;
  const int y0 = (threadIdx.x >> 4) * 4;
  float acc[4][4];
  #pragma unroll
  for (int i = 0; i < 4; ++i)
    #pragma unroll
    for (int j = 0; j < 4; ++j) acc[i][j] = 0.f;

  #pragma unroll
  for (int ty = 0; ty < 10; ++ty){
    const float* rp = &tile[(y0 + ty)*72 + x0];
    float r[12];
    *(float4*)&r[0] = *(const float4*)&rp[0];
    *(float4*)&r[4] = *(const float4*)&rp[4];
    *(float4*)&r[8] = *(const float4*)&rp[8];
    #pragma unroll
    for (int oy = 0; oy < 4; ++oy){
      if (ty >= oy && ty - oy <= 6){
        const int ky = ty - oy;
        #pragma unroll
        for (int ox = 0; ox < 4; ++ox)
          #pragma unroll
          for (int kx = 0; kx < 7; ++kx)
            acc[oy][ox] += w[ky*7 + kx] * r[ox + kx];
      }
    }
  }
  #pragma unroll
  for (int oy = 0; oy < 4; ++oy){
    const size_t gi = base + (size_t)(y0 + oy)*64 + x0;
    float4 res = *(const float4*)&io[gi];
    ushort4 pk;
    pk.x = f2bf(res.x + acc[oy][0]);
    pk.y = f2bf(res.y + acc[oy][1]);
    pk.z = f2bf(res.z + acc[oy][2]);
    pk.w = f2bf(res.w + acc[oy][3]);
    *(ushort4*)&vimg[gi] = pk;
  }
}

// ---------------------------------------------------------------------------
// Kernel 5: proj GEMM per image row (MFMA), reads bf16 sum image (vimg),
// writes final fp32 out. Staging is a pure u16x8 copy-transpose.
// ---------------------------------------------------------------------------
__global__ __launch_bounds__(256) void k_proj(
    const u16* __restrict__ pwb, const float* __restrict__ pb,
    const u16* __restrict__ vimg, float* __restrict__ io){
  const int row = blockIdx.x;           // b*64 + y
  const int b = row >> 6, y = row & 63;
  __shared__ __align__(16) u16 ts[64*264];   // [pixel n][c] bf16, pad +8
  const u16* tbase = vimg + (size_t)b*256*4096 + (size_t)y*64;
  for (int i = threadIdx.x; i < 2048; i += 256){
    const int c = i >> 3, x8 = (i & 7) * 8;
    u16x8 v = *(const u16x8*)&tbase[(size_t)c*4096 + x8];
    #pragma unroll
    for (int j = 0; j < 8; ++j) ts[(x8+j)*264 + c] = v[j];
  }
  __syncthreads();
  const int wave = threadIdx.x >> 6, lane = threadIdx.x & 63;
  const int quad = lane >> 4, l16 = lane & 15;
  const f32x4 zero4 = {0.f, 0.f, 0.f, 0.f};
  #pragma unroll
  for (int op = 0; op < 2; ++op){        // o-tile pairs
    bf16x8 af2[2][8];
    #pragma unroll
    for (int oj = 0; oj < 2; ++oj){
      const int orow = (wave*4 + op*2 + oj)*16 + l16;
      #pragma unroll
      for (int kc = 0; kc < 8; ++kc)
        af2[oj][kc] = *(const bf16x8*)(pwb + (size_t)orow*256 + kc*32 + quad*8);
    }
    f32x4 acc[2][4];
    #pragma unroll
    for (int oj = 0; oj < 2; ++oj)
      #pragma unroll
      for (int nt = 0; nt < 4; ++nt) acc[oj][nt] = zero4;
    #pragma unroll
    for (int kc = 0; kc < 8; ++kc){
      bf16x8 bf[4];
      #pragma unroll
      for (int nt = 0; nt < 4; ++nt)
        bf[nt] = *(const bf16x8*)&ts[(nt*16 + l16)*264 + kc*32 + quad*8];
      #pragma unroll
      for (int oj = 0; oj < 2; ++oj)
        #pragma unroll
        for (int nt = 0; nt < 4; ++nt)
          acc[oj][nt] = __builtin_amdgcn_mfma_f32_16x16x32_bf16(af2[oj][kc], bf[nt], acc[oj][nt], 0, 0, 0);
    }
    #pragma unroll
    for (int oj = 0; oj < 2; ++oj){
      const int ot = wave*4 + op*2 + oj;
      #pragma unroll
      for (int nt = 0; nt < 4; ++nt)
        #pragma unroll
        for (int r = 0; r < 4; ++r){
          const int o = ot*16 + quad*4 + r;
          io[((size_t)(b*256 + o))*4096 + (size_t)y*64 + nt*16 + l16] = acc[oj][nt][r] + pb[o];
        }
    }
  }
}

// ---------------------------------------------------------------------------
extern "C" void kernel_launch(void* const* d_in, const int* in_sizes, int n_in,
                              void* d_out, int out_size, void* d_ws, size_t ws_size,
                              hipStream_t stream){
  const float* x   = (const float*)d_in[0];
  const float* qw  = (const float*)d_in[1];
  const float* qb  = (const float*)d_in[2];
  const float* pw  = (const float*)d_in[3];
  const float* pb  = (const float*)d_in[4];
  const float* w1  = (const float*)d_in[5];
  const float* b1  = (const float*)d_in[6];
  const float* w2  = (const float*)d_in[7];
  const float* dww = (const float*)d_in[8];

  // ws: tab 8KB | biasQ 128KB | qwb 384KB | pwb 128KB | vimg 32MB (~34.2 MB)
  char* ws = (char*)d_ws;
  float* tab   = (float*)(ws);
  float* biasQ = (float*)(ws + 8192);
  u16*   qwb   = (u16*)  (ws + 139264);
  u16*   pwb   = (u16*)  (ws + 532480);
  u16*   vimg  = (u16*)  (ws + 663552);
  float* out   = (float*)d_out;          // attn O image (fp32), then final out

  k_cvt_w      <<<1024, 256, 0, stream>>>(qw, pw, qwb, pwb);
  k_cpb_mlp    <<<225,  256, 0, stream>>>(w1, b1, w2, tab);
  k_bias_expand<<<128,  256, 0, stream>>>(tab, biasQ);
  k_qkv_attn   <<<1024, 512, 0, stream>>>(x, qwb, qb, biasQ, out, vimg);
  k_dwconv     <<<4096, 256, 0, stream>>>(out, dww, vimg);   // vimg := bf16(O+pe)
  k_proj       <<<1024, 256, 0, stream>>>(pwb, pb, vimg, out);
}

// Round 7
// 305.138 us; speedup vs baseline: 1.1284x; 1.0162x over previous
//
#include <hip/hip_runtime.h>
#include <cstdint>
#include <cstddef>

typedef unsigned short u16;
typedef unsigned int   u32;

#define LW     15
#define BNS    0.9999950000374997f   /* 1/sqrt(1+1e-5) */
#define SCALE  0.17677669529663687f  /* 1/sqrt(32) */

typedef __bf16 bf16x8 __attribute__((ext_vector_type(8)));
typedef float  f32x4  __attribute__((ext_vector_type(4)));
typedef u16    u16x8  __attribute__((ext_vector_type(8)));

__device__ __forceinline__ u16 f2bf(float f){
  union { float f; u32 i; } v; v.f = f;
  u32 r = v.i + 0x7FFFu + ((v.i >> 16) & 1u);
  return (u16)(r >> 16);
}
__device__ __forceinline__ float bf2f(u16 u){
  union { u32 i; float f; } v; v.i = ((u32)u) << 16; return v.f;
}

// ---------------------------------------------------------------------------
// Kernel 0: convert qkv_w (196608) and proj_w (65536) fp32 -> bf16 in ws
// ---------------------------------------------------------------------------
__global__ void k_cvt_w(const float* __restrict__ qw, const float* __restrict__ pw,
                        u16* __restrict__ qwb, u16* __restrict__ pwb){
  const int i = blockIdx.x*256 + threadIdx.x;
  if (i < 196608) qwb[i] = f2bf(qw[i]);
  else            pwb[i - 196608] = f2bf(pw[i - 196608]);
}

// ---------------------------------------------------------------------------
// Kernel 1: CPB MLP -> tab[225][8] fp32
// ---------------------------------------------------------------------------
__global__ void k_cpb_mlp(const float* __restrict__ w1, const float* __restrict__ b1,
                          const float* __restrict__ w2, float* __restrict__ tab){
  const int e = blockIdx.x;        // 0..224
  const int c = threadIdx.x;       // 0..255
  const float a0 = (float)(e / LW - 7);
  const float a1 = (float)(e % LW - 7);
  const float cx = copysignf(log2f(fabsf(a0)*(8.f/7.f) + 1.f) * (1.f/3.f), a0);
  const float cy = copysignf(log2f(fabsf(a1)*(8.f/7.f) + 1.f) * (1.f/3.f), a1);
  float pre = (cx*w1[2*c] + cy*w1[2*c+1] + b1[c]) * BNS;
  float hid = pre / (1.f + __expf(-pre));   // silu
  __shared__ float hl[256];
  hl[c] = hid;
  __syncthreads();
  if (c < 8){
    float s = 0.f;
    for (int i = 0; i < 256; ++i) s += hl[i] * w2[c*256 + i];
    tab[e*8 + c] = s * BNS;
  }
}

// ---------------------------------------------------------------------------
// Kernel 2: biasQ[h][query q][key] = 16*sigmoid(tab[rpi(q,key)][h])
// ---------------------------------------------------------------------------
__global__ void k_bias_expand(const float* __restrict__ tab, float* __restrict__ biasQ){
  const int id = blockIdx.x*256 + threadIdx.x;   // h*4096 + q*64 + key
  const int key = id & 63;
  const int q   = (id >> 6) & 63;
  const int h   = id >> 12;
  const int dy = (q >> 3) - (key >> 3) + 7;
  const int dx = (q & 7)  - (key & 7)  + 7;
  const float v = tab[(dy*LW + dx)*8 + h];
  biasQ[id] = 16.f / (1.f + __expf(-v));
}

// ---------------------------------------------------------------------------
// Kernel 3: fused qkv GEMM + attention, WAVE-PER-HEAD, ONE barrier.
// R3 dataflow (best measured: 139 us, 4608 B/wave bounce) plus:
//  - q weight frags (16 x b128, 64 VGPR) loaded ABOVE the staging barrier:
//    compiler cannot sink loads across __syncthreads, so q-weight latency
//    hides under x staging for free. k/v keep R3 half-K batches.
//  - O and V stored WINDOW-MAJOR ([win][256 c][64 n]) -> every store is a
//    full 64B-line write (was 16-32B scattered chunks; write-allocate fills
//    cost ~100 MB extra HBM traffic, measured FETCH 136 vs ideal ~72).
// LDS: xs 33792 + 8*4608 = 70656 -> 2 blocks/CU.
// ---------------------------------------------------------------------------
__global__ __launch_bounds__(512, 2) void k_qkv_attn(
    const float* __restrict__ x, const u16* __restrict__ qwb,
    const float* __restrict__ qb, const float* __restrict__ biasQ,
    float* __restrict__ ow, u16* __restrict__ vw){
  const int win = blockIdx.x;
  const int b = win >> 6, wy = (win >> 3) & 7, wx = win & 7;
  __shared__ __align__(16) char smem[70656];
  u16* xs = (u16*)smem;                              // [64 tok][264 c]
  const int tid  = threadIdx.x;
  const int wave = tid >> 6, lane = tid & 63;
  const int quad = lane >> 4, l16 = lane & 15;
  u16* vbw = (u16*)(smem + 33792 + wave*4608);       // per-wave bounce
  const int h = wave;

  // ---- q weight prefetch (issued BEFORE staging; latency hides there) ----
  bf16x8 afq[2][8];
  #pragma unroll
  for (int rt = 0; rt < 2; ++rt){
    const int wr = h*32 + rt*16 + l16;               // sec = 0 (q)
    #pragma unroll
    for (int kc = 0; kc < 8; ++kc)
      afq[rt][kc] = *(const bf16x8*)(qwb + (size_t)wr*256 + kc*32 + quad*8);
  }

  // ---- stage x -> xs bf16 [tok][c] ----
  const float* xbase = x + (size_t)b*256*4096 + (size_t)(wy*8)*64 + wx*8;
  for (int i = tid; i < 4096; i += 512){
    const int c  = i >> 4;
    const int g  = i & 15;
    const int py = g >> 1, xh = (g & 1) * 4;
    float4 v4 = *(const float4*)&xbase[(size_t)c*4096 + py*64 + xh];
    const int n0 = py*8 + xh;
    xs[(n0+0)*264 + c] = f2bf(v4.x);
    xs[(n0+1)*264 + c] = f2bf(v4.y);
    xs[(n0+2)*264 + c] = f2bf(v4.z);
    xs[(n0+3)*264 + c] = f2bf(v4.w);
  }
  __syncthreads();   // the ONLY barrier

  const f32x4 zero4 = {0.f, 0.f, 0.f, 0.f};

  // GEMM with preloaded full-K weight frags (used for q).
  auto run_gemm_pre = [&](const bf16x8 (&af)[2][8], int sec, u32 (&w)[2][4][2]){
    f32x4 acc[2][4];
    #pragma unroll
    for (int rt = 0; rt < 2; ++rt)
      #pragma unroll
      for (int tt = 0; tt < 4; ++tt) acc[rt][tt] = zero4;
    #pragma unroll
    for (int kc = 0; kc < 8; ++kc){
      #pragma unroll
      for (int tt = 0; tt < 4; ++tt){
        bf16x8 bf = *(const bf16x8*)&xs[(tt*16 + l16)*264 + kc*32 + quad*8];
        acc[0][tt] = __builtin_amdgcn_mfma_f32_16x16x32_bf16(af[0][kc], bf, acc[0][tt], 0, 0, 0);
        acc[1][tt] = __builtin_amdgcn_mfma_f32_16x16x32_bf16(af[1][kc], bf, acc[1][tt], 0, 0, 0);
      }
    }
    #pragma unroll
    for (int rt = 0; rt < 2; ++rt){
      float4 b4 = *(const float4*)&qb[sec*256 + h*32 + rt*16 + quad*4];
      #pragma unroll
      for (int tt = 0; tt < 4; ++tt){
        w[rt][tt][0] = (u32)f2bf(acc[rt][tt][0] + b4.x) |
                       ((u32)f2bf(acc[rt][tt][1] + b4.y) << 16);
        w[rt][tt][1] = (u32)f2bf(acc[rt][tt][2] + b4.z) |
                       ((u32)f2bf(acc[rt][tt][3] + b4.w) << 16);
      }
    }
  };

  // R3 half-K-batched GEMM (k, v sections).
  auto run_gemm = [&](int sec, u32 (&w)[2][4][2]){
    f32x4 acc[2][4];
    #pragma unroll
    for (int rt = 0; rt < 2; ++rt)
      #pragma unroll
      for (int tt = 0; tt < 4; ++tt) acc[rt][tt] = zero4;
    #pragma unroll
    for (int kh2 = 0; kh2 < 2; ++kh2){
      bf16x8 af[2][4];
      #pragma unroll
      for (int rt = 0; rt < 2; ++rt){
        const int wr = sec*256 + h*32 + rt*16 + l16;
        #pragma unroll
        for (int kc = 0; kc < 4; ++kc)
          af[rt][kc] = *(const bf16x8*)(qwb + (size_t)wr*256 + (kh2*4 + kc)*32 + quad*8);
      }
      #pragma unroll
      for (int kc = 0; kc < 4; ++kc){
        #pragma unroll
        for (int tt = 0; tt < 4; ++tt){
          bf16x8 bf = *(const bf16x8*)&xs[(tt*16 + l16)*264 + (kh2*4 + kc)*32 + quad*8];
          acc[0][tt] = __builtin_amdgcn_mfma_f32_16x16x32_bf16(af[0][kc], bf, acc[0][tt], 0, 0, 0);
          acc[1][tt] = __builtin_amdgcn_mfma_f32_16x16x32_bf16(af[1][kc], bf, acc[1][tt], 0, 0, 0);
        }
      }
    }
    #pragma unroll
    for (int rt = 0; rt < 2; ++rt){
      float4 b4 = *(const float4*)&qb[sec*256 + h*32 + rt*16 + quad*4];
      #pragma unroll
      for (int tt = 0; tt < 4; ++tt){
        w[rt][tt][0] = (u32)f2bf(acc[rt][tt][0] + b4.x) |
                       ((u32)f2bf(acc[rt][tt][1] + b4.y) << 16);
        w[rt][tt][1] = (u32)f2bf(acc[rt][tt][2] + b4.z) |
                       ((u32)f2bf(acc[rt][tt][3] + b4.w) << 16);
      }
    }
  };

  // D-layout -> [tok][d] bounce (two 32-token halves), read back as frags.
  auto bounce_td = [&](const u32 (&w)[2][4][2], bf16x8 (&frag)[4]){
    #pragma unroll
    for (int half = 0; half < 2; ++half){
      #pragma unroll
      for (int t2 = 0; t2 < 2; ++t2){     // tt = half*2 + t2
        const int tt = half*2 + t2;
        #pragma unroll
        for (int rt = 0; rt < 2; ++rt)
          #pragma unroll
          for (int u = 0; u < 2; ++u)
            *(u32*)&vbw[(t2*16 + l16)*40 + rt*16 + quad*4 + 2*u] = w[rt][tt][u];
      }
      #pragma unroll
      for (int t2 = 0; t2 < 2; ++t2)
        frag[half*2 + t2] = *(const bf16x8*)&vbw[(t2*16 + l16)*40 + quad*8];
    }
  };

  // ---- q, k GEMMs -> register fragments ----
  bf16x8 qf[4], ka[4];
  {
    u32 wq[2][4][2];
    run_gemm_pre(afq, 0, wq);
    bounce_td(wq, qf);
  }
  {
    u32 wk[2][4][2];
    run_gemm(1, wk);
    bounce_td(wk, ka);
  }

  // ---- QK^T + softmax + P (per query-tile), bounce to A-layout pa ----
  bf16x8 pa[4][2];
  #pragma unroll
  for (int qt = 0; qt < 4; ++qt){
    f32x4 st[4];
    #pragma unroll
    for (int kt = 0; kt < 4; ++kt)
      st[kt] = __builtin_amdgcn_mfma_f32_16x16x32_bf16(ka[kt], qf[qt], zero4, 0, 0, 0);
    float4 bq[4];
    #pragma unroll
    for (int kt = 0; kt < 4; ++kt)
      bq[kt] = *(const float4*)&biasQ[(h<<12) + (qt*16 + l16)*64 + kt*16 + quad*4];
    float sc[16], mx = -1e30f;
    #pragma unroll
    for (int kt = 0; kt < 4; ++kt)
      #pragma unroll
      for (int r = 0; r < 4; ++r){
        const float v = st[kt][r]*SCALE + ((const float*)&bq[kt])[r];
        sc[kt*4+r] = v; mx = fmaxf(mx, v);
      }
    mx = fmaxf(mx, __shfl_xor(mx, 16));
    mx = fmaxf(mx, __shfl_xor(mx, 32));
    float sum = 0.f;
    #pragma unroll
    for (int i = 0; i < 16; ++i){ sc[i] = __expf(sc[i] - mx); sum += sc[i]; }
    sum += __shfl_xor(sum, 16);
    sum += __shfl_xor(sum, 32);
    const float inv = 1.f / sum;
    #pragma unroll
    for (int kt = 0; kt < 4; ++kt){
      u32 w0 = (u32)f2bf(sc[kt*4+0]*inv) | ((u32)f2bf(sc[kt*4+1]*inv) << 16);
      u32 w1 = (u32)f2bf(sc[kt*4+2]*inv) | ((u32)f2bf(sc[kt*4+3]*inv) << 16);
      *(u32*)&vbw[l16*72 + kt*16 + quad*4 + 0] = w0;
      *(u32*)&vbw[l16*72 + kt*16 + quad*4 + 2] = w1;
    }
    pa[qt][0] = *(const bf16x8*)&vbw[l16*72 +  0 + quad*8];
    pa[qt][1] = *(const bf16x8*)&vbw[l16*72 + 32 + quad*8];
  }

  // ---- v GEMM -> transposed bounce [32 d][72 tok] ----
  {
    u32 wv[2][4][2];
    run_gemm(2, wv);
    #pragma unroll
    for (int rt = 0; rt < 2; ++rt)
      #pragma unroll
      for (int tt = 0; tt < 4; ++tt)
        #pragma unroll
        for (int u = 0; u < 2; ++u){
          vbw[(rt*16 + quad*4 + 2*u + 0)*72 + tt*16 + l16] = (u16)(wv[rt][tt][u] & 0xFFFFu);
          vbw[(rt*16 + quad*4 + 2*u + 1)*72 + tt*16 + l16] = (u16)(wv[rt][tt][u] >> 16);
        }
  }
  bf16x8 bv[2][2];
  #pragma unroll
  for (int dt = 0; dt < 2; ++dt)
    #pragma unroll
    for (int kh = 0; kh < 2; ++kh)
      bv[dt][kh] = *(const bf16x8*)&vbw[(dt*16 + l16)*72 + kh*32 + quad*8];

  // ---- V store, WINDOW-MAJOR [win][256 c][64 n]: full-line writes ----
  {
    const int d = lane >> 1;
    #pragma unroll
    for (int i = 0; i < 4; ++i){
      const int ch = (lane & 1)*4 + i;
      u16x8 v8 = *(const u16x8*)&vbw[d*72 + ch*8];
      *(u16x8*)&vw[(size_t)win*16384 + (h*32 + d)*64 + ch*8] = v8;
    }
  }

  // ---- PV + normalized O store, WINDOW-MAJOR: full 64B-line writes ----
  #pragma unroll
  for (int qt = 0; qt < 4; ++qt){
    #pragma unroll
    for (int dt = 0; dt < 2; ++dt){
      f32x4 o = __builtin_amdgcn_mfma_f32_16x16x32_bf16(pa[qt][0], bv[dt][0], zero4, 0, 0, 0);
      o = __builtin_amdgcn_mfma_f32_16x16x32_bf16(pa[qt][1], bv[dt][1], o, 0, 0, 0);
      float4 o4; o4.x = o[0]; o4.y = o[1]; o4.z = o[2]; o4.w = o[3];
      *(float4*)&ow[(size_t)win*16384 + (h*32 + dt*16 + l16)*64 + qt*16 + quad*4] = o4;
    }
  }
}

// ---------------------------------------------------------------------------
// Kernel 4: depthwise 7x7 + residual. Reads v (window-major bf16) and O
// (window-major fp32); writes bf16(O + pe) WINDOW-MAJOR IN PLACE into vw.
// Safe: block (b,c) stages exactly the chunk set it later writes, all reads
// complete before the barrier; other blocks never touch channel c's chunks.
// ---------------------------------------------------------------------------
__global__ __launch_bounds__(256) void k_dwconv(
    const float* __restrict__ ow, const float* __restrict__ dww,
    u16* __restrict__ vw){
  const int b = blockIdx.x >> 8, c = blockIdx.x & 255;
  __shared__ float tile[70*72];   // zero-padded halo
  const size_t wb = (size_t)b*64*16384 + (size_t)c*64;  // [win][c][n] element offset
  for (int i = threadIdx.x; i < 1260; i += 256)
    *(float4*)&tile[i*4] = (float4){0.f, 0.f, 0.f, 0.f};
  float w[49];
  #pragma unroll
  for (int j = 0; j < 49; ++j) w[j] = dww[c*49 + j];
  __syncthreads();
  // stage: 512 chunks = 64 wins x 8 pixel-rows, 16B each (line-dense)
  for (int i = threadIdx.x; i < 512; i += 256){
    const int win = i >> 3, py = i & 7;
    u16x8 v = *(const u16x8*)&vw[wb + (size_t)win*16384 + py*8];
    const int y = ((win >> 3) << 3) + py, xw = (win & 7)*8;
    float* dst = &tile[(y+3)*72 + xw + 3];
    #pragma unroll
    for (int j = 0; j < 8; ++j) dst[j] = bf2f(v[j]);
  }
  __syncthreads();

  const int x0 = (threadIdx.x & 15) * 4;
  const int y0 = (threadIdx.x >> 4) * 4;
  float acc[4][4];
  #pragma unroll
  for (int i = 0; i < 4; ++i)
    #pragma unroll
    for (int j = 0; j < 4; ++j) acc[i][j] = 0.f;

  #pragma unroll
  for (int ty = 0; ty < 10; ++ty){
    const float* rp = &tile[(y0 + ty)*72 + x0];
    float r[12];
    *(float4*)&r[0] = *(const float4*)&rp[0];
    *(float4*)&r[4] = *(const float4*)&rp[4];
    *(float4*)&r[8] = *(const float4*)&rp[8];
    #pragma unroll
    for (int oy = 0; oy < 4; ++oy){
      if (ty >= oy && ty - oy <= 6){
        const int ky = ty - oy;
        #pragma unroll
        for (int ox = 0; ox < 4; ++ox)
          #pragma unroll
          for (int kx = 0; kx < 7; ++kx)
            acc[oy][ox] += w[ky*7 + kx] * r[ox + kx];
      }
    }
  }
  const int winx = x0 >> 3;
  #pragma unroll
  for (int oy = 0; oy < 4; ++oy){
    const int y   = y0 + oy;
    const int win = ((y >> 3) << 3) + winx;
    const int n0  = (y & 7)*8 + (x0 & 7);
    const size_t off = wb + (size_t)win*16384 + n0;   // same index for ow & vw
    float4 res = *(const float4*)&ow[off];
    ushort4 pk;
    pk.x = f2bf(res.x + acc[oy][0]);
    pk.y = f2bf(res.y + acc[oy][1]);
    pk.z = f2bf(res.z + acc[oy][2]);
    pk.w = f2bf(res.w + acc[oy][3]);
    *(ushort4*)&vw[off] = pk;
  }
}

// ---------------------------------------------------------------------------
// Kernel 5: proj GEMM per image row (MFMA), reads window-major bf16 sum (vw),
// writes final fp32 out (image layout, lane-coalesced full lines).
// ---------------------------------------------------------------------------
__global__ __launch_bounds__(256) void k_proj(
    const u16* __restrict__ pwb, const float* __restrict__ pb,
    const u16* __restrict__ vw, float* __restrict__ io){
  const int row = blockIdx.x;           // b*64 + y
  const int b = row >> 6, y = row & 63;
  const int wy = y >> 3, py = y & 7;
  __shared__ __align__(16) u16 ts[64*264];   // [pixel n][c] bf16, pad +8
  for (int i = threadIdx.x; i < 2048; i += 256){
    const int c = i >> 3, g = i & 7;        // g = window-x
    u16x8 v = *(const u16x8*)&vw[((size_t)(b*64 + wy*8 + g))*16384 + c*64 + py*8];
    const int x8 = g*8;
    #pragma unroll
    for (int j = 0; j < 8; ++j) ts[(x8+j)*264 + c] = v[j];
  }
  __syncthreads();
  const int wave = threadIdx.x >> 6, lane = threadIdx.x & 63;
  const int quad = lane >> 4, l16 = lane & 15;
  const f32x4 zero4 = {0.f, 0.f, 0.f, 0.f};
  #pragma unroll
  for (int op = 0; op < 2; ++op){        // o-tile pairs
    bf16x8 af2[2][8];
    #pragma unroll
    for (int oj = 0; oj < 2; ++oj){
      const int orow = (wave*4 + op*2 + oj)*16 + l16;
      #pragma unroll
      for (int kc = 0; kc < 8; ++kc)
        af2[oj][kc] = *(const bf16x8*)(pwb + (size_t)orow*256 + kc*32 + quad*8);
    }
    f32x4 acc[2][4];
    #pragma unroll
    for (int oj = 0; oj < 2; ++oj)
      #pragma unroll
      for (int nt = 0; nt < 4; ++nt) acc[oj][nt] = zero4;
    #pragma unroll
    for (int kc = 0; kc < 8; ++kc){
      bf16x8 bf[4];
      #pragma unroll
      for (int nt = 0; nt < 4; ++nt)
        bf[nt] = *(const bf16x8*)&ts[(nt*16 + l16)*264 + kc*32 + quad*8];
      #pragma unroll
      for (int oj = 0; oj < 2; ++oj)
        #pragma unroll
        for (int nt = 0; nt < 4; ++nt)
          acc[oj][nt] = __builtin_amdgcn_mfma_f32_16x16x32_bf16(af2[oj][kc], bf[nt], acc[oj][nt], 0, 0, 0);
    }
    #pragma unroll
    for (int oj = 0; oj < 2; ++oj){
      const int ot = wave*4 + op*2 + oj;
      #pragma unroll
      for (int nt = 0; nt < 4; ++nt)
        #pragma unroll
        for (int r = 0; r < 4; ++r){
          const int o = ot*16 + quad*4 + r;
          io[((size_t)(b*256 + o))*4096 + (size_t)y*64 + nt*16 + l16] = acc[oj][nt][r] + pb[o];
        }
    }
  }
}

// ---------------------------------------------------------------------------
extern "C" void kernel_launch(void* const* d_in, const int* in_sizes, int n_in,
                              void* d_out, int out_size, void* d_ws, size_t ws_size,
                              hipStream_t stream){
  const float* x   = (const float*)d_in[0];
  const float* qw  = (const float*)d_in[1];
  const float* qb  = (const float*)d_in[2];
  const float* pw  = (const float*)d_in[3];
  const float* pb  = (const float*)d_in[4];
  const float* w1  = (const float*)d_in[5];
  const float* b1  = (const float*)d_in[6];
  const float* w2  = (const float*)d_in[7];
  const float* dww = (const float*)d_in[8];

  // ws: tab 8KB | biasQ 128KB | qwb 384KB | pwb 128KB | vw 32MB (~34.2 MB)
  char* ws = (char*)d_ws;
  float* tab   = (float*)(ws);
  float* biasQ = (float*)(ws + 8192);
  u16*   qwb   = (u16*)  (ws + 139264);
  u16*   pwb   = (u16*)  (ws + 532480);
  u16*   vw    = (u16*)  (ws + 663552);
  float* out   = (float*)d_out;   // window-major O scratch, then final image out

  k_cvt_w      <<<1024, 256, 0, stream>>>(qw, pw, qwb, pwb);
  k_cpb_mlp    <<<225,  256, 0, stream>>>(w1, b1, w2, tab);
  k_bias_expand<<<128,  256, 0, stream>>>(tab, biasQ);
  k_qkv_attn   <<<1024, 512, 0, stream>>>(x, qwb, qb, biasQ, out, vw);
  k_dwconv     <<<4096, 256, 0, stream>>>(out, dww, vw);   // vw := bf16(O+pe), window-major
  k_proj       <<<1024, 256, 0, stream>>>(pwb, pb, vw, out);
}